// Round 2
// baseline (106.159 us; speedup 1.0000x reference)
//
#include <hip/hip_runtime.h>

#define HH 512
#define WW 512
#define NIMG 16
#define RAD 4
#define SEG 16          // output rows per thread
#define EPSF 1e-5f
#define INV81 0.012345679012345679f

// One x-column per thread, SEG output rows. Register ring of 9 horizontal
// window-sums per channel (I, J, I2, J2, IJ) + running vertical sums.
// Everything fully unrolled -> all ring indices compile-time (no scratch,
// no shift moves). Interior threads (x in [4,508)) skip x bounds checks.
__global__ __launch_bounds__(256) void ncc_main(const float* __restrict__ Iin,
                                                const float* __restrict__ Jin,
                                                double* __restrict__ acc) {
    const int tid = threadIdx.x;
    const int bid = blockIdx.x;
    const int xt  = bid & 1;          // 2 x-tiles of 256
    const int seg = (bid >> 1) & 31;  // 32 segments of 16 rows
    const int n   = bid >> 6;         // image index
    const int x   = xt * 256 + tid;
    const int y0  = seg * SEG;

    const float* Ib = Iin + (size_t)n * (HH * WW) + x;
    const float* Jb = Jin + (size_t)n * (HH * WW) + x;
    const bool interior = (x >= RAD) && (x < WW - RAD);

    float rSI[9], rSJ[9], rSI2[9], rSJ2[9], rSIJ[9];
    float VI = 0.f, VJ = 0.f, VI2 = 0.f, VJ2 = 0.f, VIJ = 0.f;

    auto hrow = [&](int yy, float& sI, float& sJ, float& sI2, float& sJ2, float& sIJ) {
        sI = 0.f; sJ = 0.f; sI2 = 0.f; sJ2 = 0.f; sIJ = 0.f;
        if (yy >= 0 && yy < HH) {       // uniform across block -> scalar branch
            const float* rI = Ib + yy * WW;
            const float* rJ = Jb + yy * WW;
            if (interior) {
                #pragma unroll
                for (int dx = -RAD; dx <= RAD; ++dx) {
                    float a = rI[dx];
                    float b = rJ[dx];
                    sI += a; sJ += b;
                    sI2 = fmaf(a, a, sI2);
                    sJ2 = fmaf(b, b, sJ2);
                    sIJ = fmaf(a, b, sIJ);
                }
            } else {
                #pragma unroll
                for (int dx = -RAD; dx <= RAD; ++dx) {
                    const int xx = x + dx;
                    const int xc = min(max(xx, 0), WW - 1) - x;  // clamped, in-bounds
                    const bool v = (xx >= 0) && (xx < WW);
                    float a = v ? rI[xc] : 0.0f;
                    float b = v ? rJ[xc] : 0.0f;
                    sI += a; sJ += b;
                    sI2 = fmaf(a, a, sI2);
                    sJ2 = fmaf(b, b, sJ2);
                    sIJ = fmaf(a, b, sIJ);
                }
            }
        }
    };

    // Warm-up: relative rows s = 0..7 (absolute y0-4 .. y0+3) into slots 0..7
    #pragma unroll
    for (int s = 0; s < 8; ++s) {
        hrow(y0 - RAD + s, rSI[s], rSJ[s], rSI2[s], rSJ2[s], rSIJ[s]);
        VI += rSI[s]; VJ += rSJ[s]; VI2 += rSI2[s]; VJ2 += rSJ2[s]; VIJ += rSIJ[s];
    }

    float local = 0.f;
    #pragma unroll
    for (int i = 0; i < SEG; ++i) {
        const int sNew = (8 + i) % 9;   // compile-time (fully unrolled)
        const int sOld = i % 9;

        hrow(y0 + i + RAD, rSI[sNew], rSJ[sNew], rSI2[sNew], rSJ2[sNew], rSIJ[sNew]);
        VI  += rSI[sNew];  VJ  += rSJ[sNew];
        VI2 += rSI2[sNew]; VJ2 += rSJ2[sNew]; VIJ += rSIJ[sNew];

        // cc = cross^2 / (Ivar*Jvar + eps); cross = VIJ - VI*VJ/81, etc.
        const float tI = VI * INV81;
        const float tJ = VJ * INV81;
        const float cross = fmaf(-tI, VJ, VIJ);
        const float Ivar  = fmaf(-tI, VI, VI2);
        const float Jvar  = fmaf(-tJ, VJ, VJ2);
        const float den   = fmaf(Ivar, Jvar, EPSF);
        local += (cross * cross) / den;

        VI  -= rSI[sOld];  VJ  -= rSJ[sOld];
        VI2 -= rSI2[sOld]; VJ2 -= rSJ2[sOld]; VIJ -= rSIJ[sOld];
    }

    // wave (64-lane) reduction
    #pragma unroll
    for (int off = 32; off > 0; off >>= 1) {
        local += __shfl_down(local, off);
    }
    __shared__ float wsum[4];
    if ((tid & 63) == 0) wsum[tid >> 6] = local;
    __syncthreads();
    if (tid == 0) {
        float b = wsum[0] + wsum[1] + wsum[2] + wsum[3];
        atomicAdd(acc, (double)b);
    }
}

__global__ void ncc_final(const double* __restrict__ acc, float* __restrict__ out) {
    out[0] = 1.0f - (float)(acc[0] * (1.0 / (double)((size_t)NIMG * HH * WW)));
}

extern "C" void kernel_launch(void* const* d_in, const int* in_sizes, int n_in,
                              void* d_out, int out_size, void* d_ws, size_t ws_size,
                              hipStream_t stream) {
    const float* I = (const float*)d_in[0];
    const float* J = (const float*)d_in[1];
    float* out = (float*)d_out;
    double* acc = (double*)d_ws;

    hipMemsetAsync(acc, 0, sizeof(double), stream);
    // 16 images * 32 segments * 2 x-tiles = 1024 blocks
    ncc_main<<<1024, 256, 0, stream>>>(I, J, acc);
    ncc_final<<<1, 1, 0, stream>>>(acc, out);
}

// Round 3
// 30.572 us; speedup vs baseline: 3.4724x; 3.4724x over previous
//
#include <hip/hip_runtime.h>

#define HH 512
#define WW 512
#define NIMG 16
#define SEG 4            // output rows per wave
#define EPSF 1e-5f
#define INV81 (1.0f / 81.0f)

// One wave per (image, 4-row strip). Lane owns 8 consecutive x columns and
// maintains 5 running column sums over the 9-row window (add y+4, sub y-4,
// old rows re-read from L1/L2 -> no register ring over rows). Horizontal
// 9-window handled with lane+-1 shuffles for the 4-column halo plus an
// in-register sliding sum. Whole row = one wave -> no LDS, no barriers.
__global__ __launch_bounds__(256, 2) void ncc_main(const float* __restrict__ Iin,
                                                   const float* __restrict__ Jin,
                                                   double* __restrict__ acc) {
    const int tid  = threadIdx.x;
    const int lane = tid & 63;
    const int gw   = blockIdx.x * 4 + (tid >> 6);   // global wave 0..2047
    const int n    = gw >> 7;                        // image (128 strips each)
    const int y0   = (gw & 127) * SEG;
    const int x0   = lane << 3;                      // 8 columns per lane

    const float* Ib = Iin + (size_t)n * (HH * WW) + x0;
    const float* Jb = Jin + (size_t)n * (HH * WW) + x0;

    float CI[8], CJ[8], CI2[8], CJ2[8], CIJ[8];
    #pragma unroll
    for (int c = 0; c < 8; ++c) { CI[c] = 0.f; CJ[c] = 0.f; CI2[c] = 0.f; CJ2[c] = 0.f; CIJ[c] = 0.f; }

    auto loadrow = [&](int r, float (&a)[8], float (&b)[8]) {
        const float4* pI = (const float4*)(Ib + (size_t)r * WW);
        const float4* pJ = (const float4*)(Jb + (size_t)r * WW);
        float4 aL = pI[0], aH = pI[1];
        float4 bL = pJ[0], bH = pJ[1];
        a[0]=aL.x; a[1]=aL.y; a[2]=aL.z; a[3]=aL.w; a[4]=aH.x; a[5]=aH.y; a[6]=aH.z; a[7]=aH.w;
        b[0]=bL.x; b[1]=bL.y; b[2]=bL.z; b[3]=bL.w; b[4]=bH.x; b[5]=bH.y; b[6]=bH.z; b[7]=bH.w;
    };

    // Warm-up: rows y0-4 .. y0+3 (clip top; y0+3 <= 511 always)
    for (int r = y0 - 4; r <= y0 + 3; ++r) {
        if (r < 0) continue;                          // wave-uniform
        float a[8], b[8];
        loadrow(r, a, b);
        #pragma unroll
        for (int c = 0; c < 8; ++c) {
            CI[c] += a[c];  CJ[c] += b[c];
            CI2[c] = fmaf(a[c], a[c], CI2[c]);
            CJ2[c] = fmaf(b[c], b[c], CJ2[c]);
            CIJ[c] = fmaf(a[c], b[c], CIJ[c]);
        }
    }

    const bool L0  = (lane == 0);
    const bool L63 = (lane == 63);

    // Horizontal box-9 across x: halo via lane+-1 shuffle, then sliding sum.
    auto hbox = [&](const float (&C)[8], float (&B)[8]) {
        float H[16];
        #pragma unroll
        for (int k = 0; k < 4; ++k) {
            float l = __shfl_up(C[4 + k], 1);
            H[k] = L0 ? 0.f : l;
        }
        #pragma unroll
        for (int k = 0; k < 8; ++k) H[4 + k] = C[k];
        #pragma unroll
        for (int k = 0; k < 4; ++k) {
            float r = __shfl_down(C[k], 1);
            H[12 + k] = L63 ? 0.f : r;
        }
        float s = ((H[0] + H[1]) + (H[2] + H[3])) + ((H[4] + H[5]) + (H[6] + H[7])) + H[8];
        B[0] = s;
        #pragma unroll
        for (int i = 1; i < 8; ++i) { s += H[i + 8] - H[i - 1]; B[i] = s; }
    };

    float local = 0.f;
    #pragma unroll 1
    for (int i = 0; i < SEG; ++i) {
        const int y = y0 + i;

        if (y + 4 < HH) {                             // add new bottom row
            float a[8], b[8];
            loadrow(y + 4, a, b);
            #pragma unroll
            for (int c = 0; c < 8; ++c) {
                CI[c] += a[c];  CJ[c] += b[c];
                CI2[c] = fmaf(a[c], a[c], CI2[c]);
                CJ2[c] = fmaf(b[c], b[c], CJ2[c]);
                CIJ[c] = fmaf(a[c], b[c], CIJ[c]);
            }
        }

        float BI[8], BJ[8], BI2[8], BJ2[8], BIJ[8];
        hbox(CI, BI); hbox(CJ, BJ); hbox(CI2, BI2); hbox(CJ2, BJ2); hbox(CIJ, BIJ);

        #pragma unroll
        for (int c = 0; c < 8; ++c) {
            const float tI = BI[c] * INV81;
            const float tJ = BJ[c] * INV81;
            const float cross = fmaf(-tI, BJ[c], BIJ[c]);
            const float Iv    = fmaf(-tI, BI[c], BI2[c]);
            const float Jv    = fmaf(-tJ, BJ[c], BJ2[c]);
            const float den   = fmaf(Iv, Jv, EPSF);
            local = fmaf(cross * cross, __builtin_amdgcn_rcpf(den), local);
        }

        if (y >= 4) {                                 // drop old top row
            float a[8], b[8];
            loadrow(y - 4, a, b);
            #pragma unroll
            for (int c = 0; c < 8; ++c) {
                CI[c] -= a[c];  CJ[c] -= b[c];
                CI2[c] = fmaf(-a[c], a[c], CI2[c]);
                CJ2[c] = fmaf(-b[c], b[c], CJ2[c]);
                CIJ[c] = fmaf(-a[c], b[c], CIJ[c]);
            }
        }
    }

    // wave reduction, then one atomic per block
    #pragma unroll
    for (int off = 32; off > 0; off >>= 1) local += __shfl_down(local, off);
    __shared__ float wsum[4];
    if (lane == 0) wsum[tid >> 6] = local;
    __syncthreads();
    if (tid == 0) {
        atomicAdd(acc, (double)(wsum[0] + wsum[1] + wsum[2] + wsum[3]));
    }
}

__global__ void ncc_final(const double* __restrict__ acc, float* __restrict__ out) {
    out[0] = 1.0f - (float)(acc[0] * (1.0 / (double)((size_t)NIMG * HH * WW)));
}

extern "C" void kernel_launch(void* const* d_in, const int* in_sizes, int n_in,
                              void* d_out, int out_size, void* d_ws, size_t ws_size,
                              hipStream_t stream) {
    const float* I = (const float*)d_in[0];
    const float* J = (const float*)d_in[1];
    float* out = (float*)d_out;
    double* acc = (double*)d_ws;

    hipMemsetAsync(acc, 0, sizeof(double), stream);
    // 2048 waves = 16 images x 128 strips; 4 waves per 256-thread block
    ncc_main<<<512, 256, 0, stream>>>(I, J, acc);
    ncc_final<<<1, 1, 0, stream>>>(acc, out);
}